// Round 13
// baseline (966.390 us; speedup 1.0000x reference)
//
#include <hip/hip_runtime.h>
#include <hip/hip_bf16.h>
#include <hip/hip_fp16.h>

typedef unsigned short u16;
typedef unsigned int u32;
typedef __attribute__((ext_vector_type(8))) _Float16 f16x8;
typedef __attribute__((ext_vector_type(4))) float f32x4;

#define ROWS 32          // 16 s/g pairs per block
#define RSTR 20          // red stride in floats (16B-aligned, bank-spread)
#define SLABH 16384      // u16 per slab half (32 frags x 512)

__device__ __forceinline__ float bf2f(u16 b) {
  union { u32 u; float f; } c; c.u = ((u32)b) << 16; return c.f;
}
__device__ __forceinline__ u16 f2bf(float f) {
  union { float f; u32 u; } c; c.f = f;
  u32 r = c.u + 0x7FFFu + ((c.u >> 16) & 1u);
  return (u16)(r >> 16);
}
__device__ __forceinline__ float gelu_tanh(float x) {
  float x2 = x * x;
  float t = __builtin_fmaf(0.044715f, x2, 1.0f);
  float e = __expf(-1.5957691216057308f * (x * t));
  return x * __builtin_amdgcn_rcpf(1.f + e);
}
__device__ __forceinline__ float ldp(const void* p, int i, int f32) {
  return f32 ? ((const float*)p)[i] : bf2f(((const u16*)p)[i]);
}
__device__ __forceinline__ f32x4 load4p(const void* p, int i, int f32) {
  if (f32) return *(const f32x4*)((const float*)p + i);
  ushort4 u = *(const ushort4*)((const u16*)p + i);
  return (f32x4){bf2f(u.x), bf2f(u.y), bf2f(u.z), bf2f(u.w)};
}
__device__ __forceinline__ f16x8 load8(const void* base, long off, int f32) {
  f16x8 r;
  if (f32) {
    const float4* p = (const float4*)((const float*)base + off);
    float4 a = p[0], b = p[1];
    r[0] = (_Float16)a.x; r[1] = (_Float16)a.y; r[2] = (_Float16)a.z; r[3] = (_Float16)a.w;
    r[4] = (_Float16)b.x; r[5] = (_Float16)b.y; r[6] = (_Float16)b.z; r[7] = (_Float16)b.w;
  } else {
    const u16* p = (const u16*)base + off;
#pragma unroll
    for (int i = 0; i < 8; ++i) r[i] = (_Float16)bf2f(p[i]);
  }
  return r;
}
// monotone (sortable) encoding of fp16 bit patterns, and decode-to-f32
__device__ __forceinline__ u32 encH(u32 h) {
  return (h & 0x8000u) ? (h ^ 0xFFFFu) : (h | 0x8000u);
}
__device__ __forceinline__ float decE(u32 e) {
  u32 h = (e & 0x8000u) ? (e & 0x7FFFu) : (~e & 0xFFFFu);
  return __half2float(__ushort_as_half((u16)h));
}
__device__ __forceinline__ u32 umin32(u32 a, u32 b) { return a < b ? a : b; }
__device__ __forceinline__ u32 umax32(u32 a, u32 b) { return a > b ? a : b; }
template <int CTRL>
__device__ __forceinline__ u32 dppx(u32 x) {
  return (u32)__builtin_amdgcn_mov_dpp((int)x, CTRL, 0xF, 0xF, false);
}
__device__ __forceinline__ u32 lxor(u32 x, int j) {
  if (j == 1) return dppx<0xB1>(x);
  if (j == 2) return dppx<0x4E>(x);
  if (j == 8) return dppx<0x128>(x);
  return (u32)__shfl_xor((int)x, j, 64);
}
__device__ __forceinline__ float lxorf(float x, int j) {
  if (j == 1) return __uint_as_float(dppx<0xB1>(__float_as_uint(x)));
  if (j == 2) return __uint_as_float(dppx<0x4E>(__float_as_uint(x)));
  if (j == 8) return __uint_as_float(dppx<0x128>(__float_as_uint(x)));
  return __shfl_xor(x, j, 64);
}

// one wave: detect dtype AND zero the c/e workspace (3x1024 floats).
__global__ void detect_dtype(const u16* __restrict__ obs, int* flag, float* ce) {
  int l = threadIdx.x;
  float v = fabsf(bf2f(obs[2 * l]));
  if (v != v) v = 1e30f;
#pragma unroll
  for (int m = 1; m <= 32; m <<= 1) v = fmaxf(v, __shfl_xor(v, m, 64));
  if (l == 0) *flag = (v > 1000.0f) ? 1 : 0;
  for (int i = l; i < 3072; i += 64) ce[i] = 0.f;
}

// LN-fold constants: for layer l in {1,2,3} (blockIdx>>3):
//   c[ch] = sum_k W_l[k][ch] * g_{l-1}[k]
//   e[ch] = sum_k W_l[k][ch] * lb_{l-1}[k] + b_l[ch]
// k-range split 8 ways (blockIdx&7), accumulated via atomicAdd (ce pre-zeroed).
__global__ void compute_ce(const void* __restrict__ W1, const void* __restrict__ W2,
                           const void* __restrict__ W3,
                           const void* __restrict__ g0, const void* __restrict__ g1,
                           const void* __restrict__ g2,
                           const void* __restrict__ h0, const void* __restrict__ h1,
                           const void* __restrict__ h2,
                           const void* __restrict__ p1, const void* __restrict__ p2,
                           const void* __restrict__ p3,
                           float* __restrict__ ce, const int* __restrict__ flag) {
  int b = blockIdx.x, l = b >> 3, kc = b & 7, ch = threadIdx.x;
  const void* W = (l == 0) ? W1 : (l == 1) ? W2 : W3;
  const void* g = (l == 0) ? g0 : (l == 1) ? g1 : g2;
  const void* hb = (l == 0) ? h0 : (l == 1) ? h1 : h2;
  const void* pb = (l == 0) ? p1 : (l == 1) ? p2 : p3;
  const int f32 = *flag;
  float c = 0.f, e = 0.f;
  for (int k = kc * 64; k < kc * 64 + 64; ++k) {
    float wv = ldp(W, k * 512 + ch, f32);
    c = __builtin_fmaf(wv, ldp(g, k, f32), c);
    e = __builtin_fmaf(wv, ldp(hb, k, f32), e);
  }
  if (kc == 0) e += ldp(pb, ch, f32);
  atomicAdd(&ce[l * 1024 + ch], c);
  atomicAdd(&ce[l * 1024 + 512 + ch], e);
}

// Pack W [K x 512] into MFMA-fragment-major fp16, optionally column-scaling by
// the previous layer's LN scale g[k] (LN folding): W'[k][ch] = W[k][ch]*g[k].
__global__ void pack_frag(const void* __restrict__ src, u16* __restrict__ dst,
                          const int* __restrict__ flag, int total,
                          int fshift, int cishift, int tmask,
                          const void* __restrict__ gscale) {
  int id = blockIdx.x * 256 + threadIdx.x;
  if (id >= total) return;
  int j = id & 7;
  int lane = (id >> 3) & 63;
  int fi = id >> 9;
  int w = fi >> fshift;
  int rem = fi & ((1 << fshift) - 1);
  int ci = rem >> cishift;
  int t = rem & tmask;
  int q = lane >> 4, r = lane & 15;
  int ch = w * 64 + ci * 16 + r;
  int k = t * 32 + q * 8 + j;
  float v = ldp(src, k * 512 + ch, *flag);
  if (gscale) v *= ldp(gscale, k, *flag);
  dst[id] = __half_as_ushort(__float2half(v));
}

// LN-folded pipeline: slab/red double-buffered; ONE barrier per layer (4 total).
// Epilogue(l) stores RAW gelu v (no LN); LN(l-1) correction is applied at the
// START of epilogue(l) as: pre = rstd*acc - mean*rstd*c[ch] + e[ch].
__global__ __launch_bounds__(512, 4) void gciqe_main(
    const void* __restrict__ obs, const void* __restrict__ goals,
    const u16* __restrict__ wT0, const u16* __restrict__ wT1,
    const u16* __restrict__ wT2, const u16* __restrict__ wT3,
    const void* __restrict__ b0, const float* __restrict__ ce,
    const void* __restrict__ alphap, void* __restrict__ out,
    const int* __restrict__ flagp)
{
  // slab halves: frag-major (frag f = nt*16+kq*4+u, 32 frags x 512 u16 each).
  // epilogue(l) writes half (l+1)&1; GEMM(l) reads half l&1. IQE reads half 0
  // (layer-3 output, same frag-major layout).
  __shared__ __align__(16) u16 slab[2 * SLABH];
  __shared__ __align__(16) float red[2 * ROWS * RSTR];

  const int f32 = *flagp;
  const int tid = threadIdx.x;
  const int lane = tid & 63, w = tid >> 6;
  const int r = lane & 15, q = lane >> 4;
  const int i0 = blockIdx.x * 16;

  f32x4 acc[4][2];

  // ---------------- layer 0: [32 x 64] @ W0 -> acc ----------------
#pragma unroll
  for (int ci = 0; ci < 4; ++ci) {
    acc[ci][0] = (f32x4){0.f, 0.f, 0.f, 0.f};
    acc[ci][1] = (f32x4){0.f, 0.f, 0.f, 0.f};
  }
  {
    f16x8 bf0[2][2];
#pragma unroll
    for (int nt = 0; nt < 2; ++nt) {
      int row = nt * 16 + r;
      const void* base = (row & 1) ? goals : obs;
      long ro = (long)(i0 + (row >> 1)) * 64;
#pragma unroll
      for (int u = 0; u < 2; ++u)
        bf0[nt][u] = load8(base, ro + u * 32 + q * 8, f32);
    }
    const u16* w0base = wT0 + w * 4096;
#pragma unroll
    for (int ci = 0; ci < 4; ++ci) {
#pragma unroll
      for (int u = 0; u < 2; ++u) {
        f16x8 af = *(const f16x8*)(w0base + (ci * 2 + u) * 512 + lane * 8);
        acc[ci][0] = __builtin_amdgcn_mfma_f32_16x16x32_f16(af, bf0[0][u], acc[ci][0], 0, 0, 0);
        acc[ci][1] = __builtin_amdgcn_mfma_f32_16x16x32_f16(af, bf0[1][u], acc[ci][1], 0, 0, 0);
      }
    }
  }

  for (int l = 0; l <= 3; ++l) {
    if (l > 0) {
      const u16* wp = (l == 1) ? wT1 : (l == 2) ? wT2 : wT3;
      const u16* wbase = wp + w * 32768;
      const u16* sb = slab + (l & 1) * SLABH;
#pragma unroll
      for (int ci = 0; ci < 4; ++ci) {
        acc[ci][0] = (f32x4){0.f, 0.f, 0.f, 0.f};
        acc[ci][1] = (f32x4){0.f, 0.f, 0.f, 0.f};
      }
      f16x8 A[2][4];
#pragma unroll
      for (int u = 0; u < 4; ++u)
        A[0][u] = *(const f16x8*)(wbase + u * 512 + lane * 8);
#pragma unroll
      for (int kq = 0; kq < 4; ++kq) {
        f16x8 bfr[2][4];
#pragma unroll
        for (int nt = 0; nt < 2; ++nt)
#pragma unroll
          for (int u = 0; u < 4; ++u)
            bfr[nt][u] = *(const f16x8*)(sb + (nt * 16 + kq * 4 + u) * 512 + lane * 8);
#pragma unroll
        for (int ci = 0; ci < 4; ++ci) {
          const int step = kq * 4 + ci;
          const int cur = step & 1;
          if (step < 15) {
            const int nstep = step + 1;
            const int nci = nstep & 3, nkq = nstep >> 2;
#pragma unroll
            for (int u = 0; u < 4; ++u)
              A[cur ^ 1][u] = *(const f16x8*)(wbase + (nci * 16 + nkq * 4 + u) * 512 + lane * 8);
          }
#pragma unroll
          for (int u = 0; u < 4; ++u) {
            acc[ci][0] = __builtin_amdgcn_mfma_f32_16x16x32_f16(A[cur][u], bfr[0][u], acc[ci][0], 0, 0, 0);
            acc[ci][1] = __builtin_amdgcn_mfma_f32_16x16x32_f16(A[cur][u], bfr[1][u], acc[ci][1], 0, 0, 0);
          }
        }
      }
    }

    // LN(l-1) correction params (l>=1): mean/rstd of previous layer's rows.
    float mean[2], rstd[2], mr[2];
    if (l > 0) {
      const float* rb = red + (l & 1) * (ROWS * RSTR);
#pragma unroll
      for (int nt = 0; nt < 2; ++nt) {
        int row = nt * 16 + r;
        float ts = 0.f, tq = 0.f;
#pragma unroll
        for (int p = 0; p < 4; ++p) {
          f32x4 a = *(const f32x4*)(rb + row * RSTR + p * 4);
          ts += a.x + a.z; tq += a.y + a.w;
        }
        mean[nt] = ts * (1.f / 512.f);
        rstd[nt] = rsqrtf(tq * (1.f / 512.f) - mean[nt] * mean[nt] + 1e-6f);
        mr[nt] = mean[nt] * rstd[nt];
      }
    }
    const float* cl = (l > 0) ? (ce + (l - 1) * 1024) : (const float*)0;
    u16* wbp = slab + ((l + 1) & 1) * SLABH;

    if (l < 3) {
      // ---- correction + gelu -> RAW v to slab[wb]; partials to red[wb] ----
      float s[2] = {0.f, 0.f}, t[2] = {0.f, 0.f};
#pragma unroll
      for (int ci = 0; ci < 4; ++ci) {
        int cb = w * 64 + ci * 16 + q * 4;
        f32x4 bb, cc, ee;
        if (l == 0) {
          bb = load4p(b0, cb, f32);
        } else {
          cc = *(const f32x4*)(cl + cb);
          ee = *(const f32x4*)(cl + 512 + cb);
        }
        int fk = ((cb >> 7) << 2) + ((cb >> 5) & 3);
        int sub = (((cb >> 3) & 3) * 16 + r) * 8 + (cb & 7);
#pragma unroll
        for (int nt = 0; nt < 2; ++nt) {
          f32x4 a = acc[ci][nt], pre;
          if (l == 0) {
            pre.x = a.x + bb.x; pre.y = a.y + bb.y;
            pre.z = a.z + bb.z; pre.w = a.w + bb.w;
          } else {
            pre.x = __builtin_fmaf(a.x, rstd[nt], __builtin_fmaf(-mr[nt], cc.x, ee.x));
            pre.y = __builtin_fmaf(a.y, rstd[nt], __builtin_fmaf(-mr[nt], cc.y, ee.y));
            pre.z = __builtin_fmaf(a.z, rstd[nt], __builtin_fmaf(-mr[nt], cc.z, ee.z));
            pre.w = __builtin_fmaf(a.w, rstd[nt], __builtin_fmaf(-mr[nt], cc.w, ee.w));
          }
          f32x4 v;
          v.x = gelu_tanh(pre.x); v.y = gelu_tanh(pre.y);
          v.z = gelu_tanh(pre.z); v.w = gelu_tanh(pre.w);
          s[nt] += v.x + v.y + v.z + v.w;
          t[nt] += v.x * v.x + v.y * v.y + v.z * v.z + v.w * v.w;
          ushort4 o;
          o.x = __half_as_ushort(__float2half(v.x));
          o.y = __half_as_ushort(__float2half(v.y));
          o.z = __half_as_ushort(__float2half(v.z));
          o.w = __half_as_ushort(__float2half(v.w));
          *(ushort4*)(wbp + (nt * 16 + fk) * 512 + sub) = o;
        }
      }
#pragma unroll
      for (int nt = 0; nt < 2; ++nt) {
        s[nt] += __shfl_xor(s[nt], 16, 64); t[nt] += __shfl_xor(t[nt], 16, 64);
        s[nt] += __shfl_xor(s[nt], 32, 64); t[nt] += __shfl_xor(t[nt], 32, 64);
      }
      if (q == 0) {
        float* wrb = red + (((l + 1) & 1)) * (ROWS * RSTR);
        *(float2*)(wrb + (0 * 16 + r) * RSTR + w * 2) = make_float2(s[0], t[0]);
        *(float2*)(wrb + (1 * 16 + r) * RSTR + w * 2) = make_float2(s[1], t[1]);
      }
      __syncthreads();   // the ONLY barrier this layer: red[wb]+slab[wb] visible
    } else {
      // ---- layer 3: correction only (= phi), frag-major to slab half 0 ----
#pragma unroll
      for (int ci = 0; ci < 4; ++ci) {
        int cb = w * 64 + ci * 16 + q * 4;
        f32x4 cc = *(const f32x4*)(cl + cb);
        f32x4 ee = *(const f32x4*)(cl + 512 + cb);
        int fk = ((cb >> 7) << 2) + ((cb >> 5) & 3);
        int sub = (((cb >> 3) & 3) * 16 + r) * 8 + (cb & 7);
#pragma unroll
        for (int nt = 0; nt < 2; ++nt) {
          f32x4 a = acc[ci][nt];
          ushort4 o;
          o.x = __half_as_ushort(__float2half(__builtin_fmaf(a.x, rstd[nt], __builtin_fmaf(-mr[nt], cc.x, ee.x))));
          o.y = __half_as_ushort(__float2half(__builtin_fmaf(a.y, rstd[nt], __builtin_fmaf(-mr[nt], cc.y, ee.y))));
          o.z = __half_as_ushort(__float2half(__builtin_fmaf(a.z, rstd[nt], __builtin_fmaf(-mr[nt], cc.z, ee.z))));
          o.w = __half_as_ushort(__float2half(__builtin_fmaf(a.w, rstd[nt], __builtin_fmaf(-mr[nt], cc.w, ee.w))));
          *(ushort4*)(wbp + (nt * 16 + fk) * 512 + sub) = o;
        }
      }
      __syncthreads();   // phi visible before IQE
    }
  }

  // ---------------- IQE head: 4-way interleaved chains, frag-major reads ----
  {
    const float al = ldp(alphap, 0, f32);
    const float aa = 1.f / (1.f + __expf(-al));
    const int h = lane >> 5, il = lane & 31;
#pragma unroll
    for (int pv = 0; pv < 2; ++pv) {
      int pL = 2 * w + pv;                      // block-local pair 0..15
      // frag-major phi: value(row, ch=32c+il) at
      // slab[((row>>4)*16 + (c>>2)*4 + (c&3))*512 + (il>>3)*128 + (row&15)*8 + (il&7)]
      const int nt3 = pL >> 3;
      const int rr8 = ((2 * pL) & 15) * 8;
      float cs = 0.f, cm = 0.f;
#pragma unroll
      for (int itb = 0; itb < 8; itb += 4) {
        u32 sv[4];
#pragma unroll
        for (int u = 0; u < 4; ++u) {
          int c = 2 * (itb + u) + h;
          int ba = (nt3 * 16 + (c >> 2) * 4 + (c & 3)) * 512 + (il >> 3) * 128 + rr8 + (il & 7);
          u32 xh = slab[ba];
          u32 yh = slab[ba + 8];
          u32 ex = encH(xh), ey = encH(yh);
          sv[u] = (ex << 16) | ((ex < ey) ? ey : 0x03FFu);
        }
#pragma unroll
        for (int k = 2; k <= 32; k <<= 1) {
#pragma unroll
          for (int j = k >> 1; j >= 1; j >>= 1) {
            const bool up = ((il & k) == 0) == ((il & j) == 0);
#pragma unroll
            for (int u = 0; u < 4; ++u) {
              u32 so = lxor(sv[u], j);
              u32 mn = umin32(sv[u], so), mx = umax32(sv[u], so);
              sv[u] = up ? mn : mx;
            }
          }
        }
        u32 ye[4], p[4];
#pragma unroll
        for (int u = 0; u < 4; ++u) {
          ye[u] = sv[u] & 0xFFFFu;
          p[u] = __shfl_up(ye[u], 1, 32);
          if (il == 0) p[u] = 0u;
        }
#pragma unroll
        for (int d = 1; d <= 16; d <<= 1) {
#pragma unroll
          for (int u = 0; u < 4; ++u) {
            u32 t2 = __shfl_up(p[u], d, 32);
            if (il >= d) p[u] = umax32(p[u], t2);
          }
        }
        float contrib[4];
#pragma unroll
        for (int u = 0; u < 4; ++u)
          contrib[u] = fmaxf(0.f, decE(ye[u]) - decE(umax32(sv[u] >> 16, p[u])));
#pragma unroll
        for (int msk = 1; msk <= 16; msk <<= 1)
#pragma unroll
          for (int u = 0; u < 4; ++u)
            contrib[u] += lxorf(contrib[u], msk);
#pragma unroll
        for (int u = 0; u < 4; ++u) {
          cs += contrib[u];
          cm = fmaxf(cm, contrib[u]);
        }
      }
      cs += __shfl_xor(cs, 32, 64);
      cm = fmaxf(cm, __shfl_xor(cm, 32, 64));
      if (lane == 0) {
        float res = aa * (cs * (1.f / 16.f)) + (1.f - aa) * cm;
        if (f32) ((float*)out)[i0 + pL] = res;
        else ((u16*)out)[i0 + pL] = f2bf(res);
      }
    }
  }
}

extern "C" void kernel_launch(void* const* d_in, const int* in_sizes, int n_in,
                              void* d_out, int out_size, void* d_ws, size_t ws_size,
                              hipStream_t stream) {
  (void)in_sizes; (void)n_in; (void)out_size; (void)ws_size;
  const void* obs   = d_in[0];
  const void* goals = d_in[1];
  const void* W0 = d_in[2];
  const void* b0 = d_in[3];
  const void* ls0 = d_in[4];
  const void* lb0 = d_in[5];
  const void* W1 = d_in[6];
  const void* b1 = d_in[7];
  const void* ls1 = d_in[8];
  const void* lb1 = d_in[9];
  const void* W2 = d_in[10];
  const void* b2 = d_in[11];
  const void* ls2 = d_in[12];
  const void* lb2 = d_in[13];
  const void* W3 = d_in[14];
  const void* b3 = d_in[15];
  const void* alpha = d_in[16];

  int* flag = (int*)d_ws;
  u16* wT0 = (u16*)((char*)d_ws + 64);
  u16* wT1 = wT0 + 512 * 64;
  u16* wT2 = wT1 + 512 * 512;
  u16* wT3 = wT2 + 512 * 512;
  float* ce = (float*)((char*)d_ws + 64 + 2 * (512 * 64 + 3 * 512 * 512));

  detect_dtype<<<1, 64, 0, stream>>>((const u16*)obs, flag, ce);
  // LN-fold constants for layers 1..3 (k split 8 ways, atomic accumulate)
  compute_ce<<<24, 512, 0, stream>>>(W1, W2, W3, ls0, ls1, ls2,
                                     lb0, lb1, lb2, b1, b2, b3, ce, flag);
  // W0: no preceding LN -> no column scale
  pack_frag<<<128, 256, 0, stream>>>(W0, wT0, flag, 512 * 64, 3, 1, 1, nullptr);
  // W1..W3: fold previous layer's LN scale into the packed weights
  pack_frag<<<1024, 256, 0, stream>>>(W1, wT1, flag, 512 * 512, 6, 4, 15, ls0);
  pack_frag<<<1024, 256, 0, stream>>>(W2, wT2, flag, 512 * 512, 6, 4, 15, ls1);
  pack_frag<<<1024, 256, 0, stream>>>(W3, wT3, flag, 512 * 512, 6, 4, 15, ls2);
  gciqe_main<<<8192, 512, 0, stream>>>(obs, goals, wT0, wT1, wT2, wT3,
      b0, ce, alpha, d_out, flag);
}